// Round 10
// baseline (10073.993 us; speedup 1.0000x reference)
//
#include <hip/hip_runtime.h>
#include <math.h>

#define B_SZ   32
#define T_SZ   1024
#define IN_SZ  512
#define SEN    512
#define HID    1024
#define MOT    512
#define OUT_SZ 512

#define NBLK   32          // scan blocks (j-slices)
#define JSL    32          // j's per block
#define K2     512         // f16-pair dwords per h row
#define WPAD   516         // padded w_lds row stride (dwords)

typedef __fp16  f16x8 __attribute__((ext_vector_type(8)));
typedef float   f32x4 __attribute__((ext_vector_type(4)));

__device__ inline uint32_t pk16(float a, float b) {
  auto p = __builtin_amdgcn_cvt_pkrtz(a, b);
  return __builtin_bit_cast(uint32_t, p);
}

// ---------------------------------------------------------------------------
// Generic tiled f32 GEMM:  C[scatter(r), c] = sum_k A[r,k] * op(B)[k,c] + bias[c]
//   TB=true : Bm is [N][K] row-major (A @ B^T);  TB=false: Bm is [K][N] (A @ B)
//   C address for row r, col c:  (r % P)*S1 + (r / P)*S2 + c
// ---------------------------------------------------------------------------
template<bool TB>
__global__ __launch_bounds__(256) void gemm_tiled(
    const float* __restrict__ A, const float* __restrict__ Bm,
    const float* __restrict__ bias, float* __restrict__ C,
    int M, int N, int K, int lda,
    int P, long long S1, long long S2)
{
  __shared__ float As[16][64 + 1];
  __shared__ float Bs[16][64 + 1];
  const int tid = threadIdx.x;
  const int n0 = blockIdx.x * 64;
  const int r0 = blockIdx.y * 64;
  const int ty = tid / 16;
  const int tx = tid % 16;

  float acc[4][4] = {};

  for (int k0 = 0; k0 < K; k0 += 16) {
    {
      const int kk = tid % 16, m0 = tid / 16;
      #pragma unroll
      for (int i = 0; i < 4; i++) {
        const int m = m0 + i * 16;
        As[kk][m] = A[(long long)(r0 + m) * lda + k0 + kk];
      }
    }
    if (TB) {
      const int kk = tid % 16, nl0 = tid / 16;
      #pragma unroll
      for (int i = 0; i < 4; i++) {
        const int n = nl0 + i * 16;
        Bs[kk][n] = Bm[(long long)(n0 + n) * K + k0 + kk];
      }
    } else {
      const int nl = tid % 64, kk0 = tid / 64;
      #pragma unroll
      for (int i = 0; i < 4; i++) {
        const int kk = kk0 + i * 4;
        Bs[kk][nl] = Bm[(long long)(k0 + kk) * N + n0 + nl];
      }
    }
    __syncthreads();

    #pragma unroll
    for (int kk = 0; kk < 16; kk++) {
      float av[4], bv[4];
      #pragma unroll
      for (int i = 0; i < 4; i++) av[i] = As[kk][ty * 4 + i];
      #pragma unroll
      for (int j = 0; j < 4; j++) bv[j] = Bs[kk][tx * 4 + j];
      #pragma unroll
      for (int i = 0; i < 4; i++)
        #pragma unroll
        for (int j = 0; j < 4; j++)
          acc[i][j] += av[i] * bv[j];
    }
    __syncthreads();
  }

  #pragma unroll
  for (int i = 0; i < 4; i++) {
    const int r = r0 + ty * 4 + i;
    const long long base = (long long)(r % P) * S1 + (long long)(r / P) * S2;
    #pragma unroll
    for (int j = 0; j < 4; j++) {
      const int c = n0 + tx * 4 + j;
      float v = acc[i][j];
      if (bias) v += bias[c];
      C[base + c] = v;
    }
  }
}

// bias_eff[h] = b_cell[h] + dot(W_x[h,:], b_in)
__global__ void bias_eff_kernel(const float* __restrict__ Wx,
                                const float* __restrict__ b_in,
                                const float* __restrict__ b_cell,
                                float* __restrict__ bias_eff)
{
  const int h = blockIdx.x * 256 + threadIdx.x;
  float s = b_cell[h];
  for (int k = 0; k < SEN; k++) s += Wx[h * SEN + k] * b_in[k];
  bias_eff[h] = s;
}

// Pack W_h f32 [j][k] -> Wp16 u32 [j][k2]
__global__ __launch_bounds__(256) void pack_wh16_kernel(
    const float* __restrict__ Wh, uint32_t* __restrict__ Wp16)
{
  const int idx = blockIdx.x * 256 + threadIdx.x;
  const float2 v = *(const float2*)(Wh + (size_t)idx * 2);
  Wp16[idx] = pk16(v.x, v.y);
}

// Pack init_h f32 [B][HID] -> hx[0] ([B][K2] u32 f16-pairs)
__global__ __launch_bounds__(256) void init_hx_kernel(
    const float* __restrict__ init_h, uint32_t* __restrict__ hx0)
{
  const int idx = blockIdx.x * 256 + threadIdx.x;      // b*K2 + k2
  const float2 v = *(const float2*)(init_h + (size_t)idx * 2);
  hx0[idx] = pk16(v.x, v.y);
}

// ---------------------------------------------------------------------------
// Scan v8: 32 blocks x 256 threads (4 waves), W slice in LDS, NO h_lds.
// Per step per block: [poll flags -> release] -> A-frags DIRECT from hx
// (device-scope relaxed 8B loads; hx layout == MFMA A-operand layout) ->
// 32x mfma_f32_16x16x32_f16 -> liquid update (exact f32 h_old in regs) ->
// publish f16 pairs -> hseq store + pre/ts prefetch -> syncthreads (drain)
// -> post own flag. hx double-buffered by parity; proven R8/R9 invariant.
// ---------------------------------------------------------------------------
__global__ __launch_bounds__(256) void scan_x_kernel(
    const float* __restrict__ init_h,
    const uint32_t* __restrict__ Wp16,   // [HID][K2]
    const float* __restrict__ pre,       // [T][B][HID]
    const float* __restrict__ tsp,       // [B][T]
    const float* __restrict__ Avec,
    const float* __restrict__ tau,
    float* __restrict__ hseq,            // [T][B][MOT]
    uint32_t* __restrict__ hx,           // [2][B][K2]
    uint32_t* __restrict__ flags,        // [NBLK][16]
    float* __restrict__ last_state)      // [B][HID]
{
  __shared__ uint32_t w_lds[JSL * WPAD];   // 66 KB

  const int bk   = blockIdx.x;
  const int tid  = threadIdx.x;
  const int wv   = tid >> 6;               // 0..3
  const int lane = tid & 63;
  const int qr   = wv >> 1;                // b-half
  const int qc   = wv & 1;                 // j-half
  const int row16 = lane & 15;
  const int kg    = lane >> 4;             // 0..3

  const int j_loc  = qc * 16 + row16;
  const int j_glob = bk * JSL + j_loc;
  const int b0     = qr * 16 + kg * 4;     // first of 4 owned b's

  // stage weight slice (once), row-padded
  {
    const uint32_t* src = Wp16 + (size_t)bk * JSL * K2;
    for (int i = tid; i < JSL * K2; i += 256)
      w_lds[(i >> 9) * WPAD + (i & (K2 - 1))] = src[i];
  }

  const float a_j  = Avec[j_glob];
  const float it_j = 1.f / tau[j_glob];
  float h_old[4];
  #pragma unroll
  for (int r = 0; r < 4; ++r) h_old[r] = init_h[(b0 + r) * HID + j_glob];

  float prevC[4], tsC[4];
  #pragma unroll
  for (int r = 0; r < 4; ++r) {
    prevC[r] = pre[(size_t)(b0 + r) * HID + j_glob];
    tsC[r]   = tsp[(b0 + r) * T_SZ + 0];
  }

  __syncthreads();

  const uint32_t* brow = &w_lds[j_loc * WPAD];
  const size_t abase = (size_t)(qr * 16 + row16) * (K2 / 2) + kg * 2;  // u64 units

  for (int t = 0; t < T_SZ; ++t) {
    // wait for all blocks to have published h(t) into parity t&1
    if (t > 0) {
      if (tid < 64) {
        const uint32_t tgt = (uint32_t)t;
        while (__hip_atomic_load(&flags[(tid & 31) * 16],
                                 __ATOMIC_RELAXED, __HIP_MEMORY_SCOPE_AGENT) < tgt)
          __builtin_amdgcn_s_sleep(1);
      }
      __syncthreads();
    }

    // A fragments directly from exchange buffer (coherent 8B loads)
    const unsigned long long* hxr =
        (const unsigned long long*)(hx + (t & 1) * (B_SZ * K2));
    f32x4 acc = {0.f, 0.f, 0.f, 0.f};
    #pragma unroll
    for (int kk = 0; kk < 32; ++kk) {
      const unsigned long long a0 =
          __hip_atomic_load(&hxr[abase + kk * 8],
                            __ATOMIC_RELAXED, __HIP_MEMORY_SCOPE_AGENT);
      const unsigned long long a1 =
          __hip_atomic_load(&hxr[abase + kk * 8 + 1],
                            __ATOMIC_RELAXED, __HIP_MEMORY_SCOPE_AGENT);
      const uint4 av = make_uint4((uint32_t)a0, (uint32_t)(a0 >> 32),
                                  (uint32_t)a1, (uint32_t)(a1 >> 32));
      const uint4 bv = *(const uint4*)(brow + kk * 16 + kg * 4);
      acc = __builtin_amdgcn_mfma_f32_16x16x32_f16(
          __builtin_bit_cast(f16x8, av), __builtin_bit_cast(f16x8, bv),
          acc, 0, 0, 0);
    }

    // liquid update for the 4 owned (b, j) cells
    float hn[4];
    #pragma unroll
    for (int r = 0; r < 4; ++r) {
      const float z = acc[r] + prevC[r];
      const float f = 1.f / (1.f + __expf(-z));
      hn[r] = (h_old[r] + tsC[r] * f * a_j) / (1.f + tsC[r] * (it_j + f));
      h_old[r] = hn[r];
    }

    // publish: pack (j, j^1) pairs via shfl_xor; even j-lanes store dwords
    uint32_t* hxw = hx + ((t + 1) & 1) * (B_SZ * K2);
    #pragma unroll
    for (int r = 0; r < 4; ++r) {
      const float partner = __shfl_xor(hn[r], 1);
      if ((row16 & 1) == 0)
        __hip_atomic_store(&hxw[(b0 + r) * K2 + bk * (JSL / 2) + (j_loc >> 1)],
                           pk16(hn[r], partner),
                           __ATOMIC_RELAXED, __HIP_MEMORY_SCOPE_AGENT);
    }
    if (bk < 16) {   // motor half -> hseq f32
      #pragma unroll
      for (int r = 0; r < 4; ++r)
        hseq[(size_t)t * (B_SZ * MOT) + (b0 + r) * MOT + j_glob] = hn[r];
    }

    // prefetch next step's pre/ts (overlaps store drain)
    const int tn = (t + 1 < T_SZ) ? t + 1 : t;
    #pragma unroll
    for (int r = 0; r < 4; ++r) {
      prevC[r] = pre[(size_t)tn * (B_SZ * HID) + (b0 + r) * HID + j_glob];
      tsC[r]   = tsp[(b0 + r) * T_SZ + tn];
    }

    __syncthreads();   // every wave drains vmcnt(0) -> hx stores visible

    if (tid == 0)
      __hip_atomic_store(&flags[bk * 16], (uint32_t)(t + 1),
                         __ATOMIC_RELAXED, __HIP_MEMORY_SCOPE_AGENT);
  }

  #pragma unroll
  for (int r = 0; r < 4; ++r)
    last_state[(b0 + r) * HID + j_glob] = h_old[r];
}

extern "C" void kernel_launch(void* const* d_in, const int* in_sizes, int n_in,
                              void* d_out, int out_size, void* d_ws, size_t ws_size,
                              hipStream_t stream)
{
  const float* inputs    = (const float*)d_in[0];
  const float* timespans = (const float*)d_in[1];
  const float* init_h    = (const float*)d_in[2];
  const float* W_in      = (const float*)d_in[3];
  const float* b_in      = (const float*)d_in[4];
  const float* W_x       = (const float*)d_in[5];
  const float* W_h       = (const float*)d_in[6];
  const float* b_cell    = (const float*)d_in[7];
  const float* tau       = (const float*)d_in[8];
  const float* A         = (const float*)d_in[9];
  const float* W_out     = (const float*)d_in[10];
  const float* b_out     = (const float*)d_in[11];
  float* out = (float*)d_out;

  float*    ws    = (float*)d_ws;
  float*    pre   = ws;                                  // T*B*HID f32
  float*    hseq  = pre   + (size_t)T_SZ * B_SZ * HID;   // T*B*MOT f32
  float*    WxiWp = hseq  + (size_t)T_SZ * B_SZ * MOT;   // HID*IN_SZ (Wxi f32 -> Wp16 u32)
  float*    beff  = WxiWp + (size_t)HID * IN_SZ;         // HID
  uint32_t* hx    = (uint32_t*)(beff + HID);             // 2*B*K2
  uint32_t* flags = hx + 2 * B_SZ * K2;                  // NBLK*16 u32

  // K0: Wxi = W_x @ W_in  (fold input projection into cell GEMM)
  gemm_tiled<false><<<dim3(IN_SZ / 64, HID / 64), 256, 0, stream>>>(
      W_x, W_in, nullptr, WxiWp, HID, IN_SZ, SEN, SEN,
      1 << 30, (long long)IN_SZ, 0LL);

  bias_eff_kernel<<<HID / 256, 256, 0, stream>>>(W_x, b_in, b_cell, beff);

  // K1: pre[t][b][h] = inputs[r=b*T+t,:] @ Wxi^T + beff
  gemm_tiled<true><<<dim3(HID / 64, (B_SZ * T_SZ) / 64), 256, 0, stream>>>(
      inputs, WxiWp, beff, pre, B_SZ * T_SZ, HID, IN_SZ, IN_SZ,
      T_SZ, (long long)B_SZ * HID, (long long)HID);

  // K2a: pack W_h -> f16x2 (overwrites Wxi slot; safe by stream order)
  pack_wh16_kernel<<<(HID * K2) / 256, 256, 0, stream>>>(W_h, (uint32_t*)WxiWp);

  // K2b: init exchange buffer parity-0; zero flags
  init_hx_kernel<<<(B_SZ * K2) / 256, 256, 0, stream>>>(init_h, hx);
  (void)hipMemsetAsync(flags, 0, NBLK * 16 * sizeof(uint32_t), stream);

  // K2c: the scan — 32 co-resident blocks
  {
    const uint32_t* Wp16c = (const uint32_t*)WxiWp;
    float* last_state = out + (size_t)B_SZ * T_SZ * OUT_SZ;
    void* args[] = {
      (void*)&init_h, (void*)&Wp16c, (void*)&pre, (void*)&timespans,
      (void*)&A, (void*)&tau, (void*)&hseq, (void*)&hx, (void*)&flags,
      (void*)&last_state
    };
    (void)hipLaunchCooperativeKernel((void*)scan_x_kernel, dim3(NBLK), dim3(256),
                                     args, 0, stream);
  }

  // K3: out[b][t][o] = hseq[r=t*B+b, :MOT] @ W_out^T + b_out
  gemm_tiled<true><<<dim3(OUT_SZ / 64, (B_SZ * T_SZ) / 64), 256, 0, stream>>>(
      hseq, W_out, b_out, out, B_SZ * T_SZ, OUT_SZ, MOT, MOT,
      B_SZ, (long long)T_SZ * OUT_SZ, (long long)OUT_SZ);
}

// Round 11
// 5200.281 us; speedup vs baseline: 1.9372x; 1.9372x over previous
//
#include <hip/hip_runtime.h>
#include <math.h>

#define B_SZ   32
#define T_SZ   1024
#define IN_SZ  512
#define SEN    512
#define HID    1024
#define MOT    512
#define OUT_SZ 512

#define NBLK   32          // scan blocks (j-slices)
#define JSL    32          // j's per block
#define K2     512         // f16-pair dwords per h row
#define WPAD   516         // padded w_lds row stride (dwords)

typedef __fp16  f16x8 __attribute__((ext_vector_type(8)));
typedef float   f32x4 __attribute__((ext_vector_type(4)));

__device__ inline uint32_t pk16(float a, float b) {
  auto p = __builtin_amdgcn_cvt_pkrtz(a, b);
  return __builtin_bit_cast(uint32_t, p);
}

// ---------------------------------------------------------------------------
// Generic tiled f32 GEMM:  C[scatter(r), c] = sum_k A[r,k] * op(B)[k,c] + bias[c]
//   TB=true : Bm is [N][K] row-major (A @ B^T);  TB=false: Bm is [K][N] (A @ B)
//   C address for row r, col c:  (r % P)*S1 + (r / P)*S2 + c
// ---------------------------------------------------------------------------
template<bool TB>
__global__ __launch_bounds__(256) void gemm_tiled(
    const float* __restrict__ A, const float* __restrict__ Bm,
    const float* __restrict__ bias, float* __restrict__ C,
    int M, int N, int K, int lda,
    int P, long long S1, long long S2)
{
  __shared__ float As[16][64 + 1];
  __shared__ float Bs[16][64 + 1];
  const int tid = threadIdx.x;
  const int n0 = blockIdx.x * 64;
  const int r0 = blockIdx.y * 64;
  const int ty = tid / 16;
  const int tx = tid % 16;

  float acc[4][4] = {};

  for (int k0 = 0; k0 < K; k0 += 16) {
    {
      const int kk = tid % 16, m0 = tid / 16;
      #pragma unroll
      for (int i = 0; i < 4; i++) {
        const int m = m0 + i * 16;
        As[kk][m] = A[(long long)(r0 + m) * lda + k0 + kk];
      }
    }
    if (TB) {
      const int kk = tid % 16, nl0 = tid / 16;
      #pragma unroll
      for (int i = 0; i < 4; i++) {
        const int n = nl0 + i * 16;
        Bs[kk][n] = Bm[(long long)(n0 + n) * K + k0 + kk];
      }
    } else {
      const int nl = tid % 64, kk0 = tid / 64;
      #pragma unroll
      for (int i = 0; i < 4; i++) {
        const int kk = kk0 + i * 4;
        Bs[kk][nl] = Bm[(long long)(k0 + kk) * N + n0 + nl];
      }
    }
    __syncthreads();

    #pragma unroll
    for (int kk = 0; kk < 16; kk++) {
      float av[4], bv[4];
      #pragma unroll
      for (int i = 0; i < 4; i++) av[i] = As[kk][ty * 4 + i];
      #pragma unroll
      for (int j = 0; j < 4; j++) bv[j] = Bs[kk][tx * 4 + j];
      #pragma unroll
      for (int i = 0; i < 4; i++)
        #pragma unroll
        for (int j = 0; j < 4; j++)
          acc[i][j] += av[i] * bv[j];
    }
    __syncthreads();
  }

  #pragma unroll
  for (int i = 0; i < 4; i++) {
    const int r = r0 + ty * 4 + i;
    const long long base = (long long)(r % P) * S1 + (long long)(r / P) * S2;
    #pragma unroll
    for (int j = 0; j < 4; j++) {
      const int c = n0 + tx * 4 + j;
      float v = acc[i][j];
      if (bias) v += bias[c];
      C[base + c] = v;
    }
  }
}

// bias_eff[h] = b_cell[h] + dot(W_x[h,:], b_in)
__global__ void bias_eff_kernel(const float* __restrict__ Wx,
                                const float* __restrict__ b_in,
                                const float* __restrict__ b_cell,
                                float* __restrict__ bias_eff)
{
  const int h = blockIdx.x * 256 + threadIdx.x;
  float s = b_cell[h];
  for (int k = 0; k < SEN; k++) s += Wx[h * SEN + k] * b_in[k];
  bias_eff[h] = s;
}

// Pack W_h f32 [j][k] -> Wp16 u32 [j][k2]
__global__ __launch_bounds__(256) void pack_wh16_kernel(
    const float* __restrict__ Wh, uint32_t* __restrict__ Wp16)
{
  const int idx = blockIdx.x * 256 + threadIdx.x;
  const float2 v = *(const float2*)(Wh + (size_t)idx * 2);
  Wp16[idx] = pk16(v.x, v.y);
}

// Pack init_h f32 [B][HID] -> hx[0] in FRAGMENT-MAJOR layout:
//   u32 index = (j>>3)*128 + b*4 + ((j>>1)&3)   (j = even element of pair)
__global__ __launch_bounds__(256) void init_hx_kernel(
    const float* __restrict__ init_h, uint32_t* __restrict__ hx0)
{
  const int idx = blockIdx.x * 256 + threadIdx.x;      // b*512 + j2
  const int b  = idx >> 9;
  const int j2 = idx & 511;                            // pair index, j = 2*j2
  const float2 v = *(const float2*)(init_h + (size_t)b * HID + 2 * j2);
  hx0[(j2 >> 2) * 128 + b * 4 + (j2 & 3)] = pk16(v.x, v.y);
}

// ---------------------------------------------------------------------------
// Scan v9: 32 blocks x 256 threads (4 waves), W slice in LDS, NO h_lds.
// hx is FRAGMENT-MAJOR: chunk c = j>>3 holds [b][4 words]; the MFMA A-operand
// for (wave qr, lane(row16,kg), iter kk) is the uint4 at
//   (kk*4+kg)*128 + (qr*16+row16)*4
// -> 16 consecutive lanes read 256B contiguous runs (fully coalesced).
// Per step: poll flags -> 64x 8B coherent loads (unrolled, deep pipeline)
// -> 32 MFMA (W from LDS, 2-way bank = free) -> liquid update (f32 regs)
// -> publish fragment-major pairs -> hseq + pre/ts prefetch -> syncthreads
// (vmcnt drain) -> post flag. Same race-free parity invariant as R8.
// ---------------------------------------------------------------------------
__global__ __launch_bounds__(256, 1) void scan_x_kernel(
    const float* __restrict__ init_h,
    const uint32_t* __restrict__ Wp16,   // [HID][K2]
    const float* __restrict__ pre,       // [T][B][HID]
    const float* __restrict__ tsp,       // [B][T]
    const float* __restrict__ Avec,
    const float* __restrict__ tau,
    float* __restrict__ hseq,            // [T][B][MOT]
    uint32_t* __restrict__ hx,           // [2][B_SZ*K2] fragment-major
    uint32_t* __restrict__ flags,        // [NBLK][16]
    float* __restrict__ last_state)      // [B][HID]
{
  __shared__ uint32_t w_lds[JSL * WPAD];   // 66 KB

  const int bk   = blockIdx.x;
  const int tid  = threadIdx.x;
  const int wv   = tid >> 6;               // 0..3
  const int lane = tid & 63;
  const int qr   = wv >> 1;                // b-half
  const int qc   = wv & 1;                 // j-half
  const int row16 = lane & 15;
  const int kg    = lane >> 4;             // 0..3

  const int j_loc  = qc * 16 + row16;
  const int j_glob = bk * JSL + j_loc;
  const int b0     = qr * 16 + kg * 4;     // first of 4 owned b's

  // stage weight slice (once), row-padded
  {
    const uint32_t* src = Wp16 + (size_t)bk * JSL * K2;
    for (int i = tid; i < JSL * K2; i += 256)
      w_lds[(i >> 9) * WPAD + (i & (K2 - 1))] = src[i];
  }

  const float a_j  = Avec[j_glob];
  const float it_j = 1.f / tau[j_glob];
  float h_old[4];
  #pragma unroll
  for (int r = 0; r < 4; ++r) h_old[r] = init_h[(b0 + r) * HID + j_glob];

  float prevC[4], tsC[4];
  #pragma unroll
  for (int r = 0; r < 4; ++r) {
    prevC[r] = pre[(size_t)(b0 + r) * HID + j_glob];
    tsC[r]   = tsp[(b0 + r) * T_SZ + 0];
  }

  __syncthreads();

  const uint32_t* brow = &w_lds[j_loc * WPAD];
  const int ab2 = (qr * 16 + row16) * 2;            // u64 base within chunk

  // publish indices (fragment-major): chunk = j_glob>>3, wrd = (j_glob>>1)&3
  const int pub_base = (j_glob >> 3) * 128 + (j_glob >> 1 & 3);

  for (int t = 0; t < T_SZ; ++t) {
    // wait for all blocks to have published h(t) into parity t&1
    if (t > 0) {
      if (tid < 64) {
        const uint32_t tgt = (uint32_t)t;
        while (__hip_atomic_load(&flags[(tid & 31) * 16],
                                 __ATOMIC_RELAXED, __HIP_MEMORY_SCOPE_AGENT) < tgt)
          __builtin_amdgcn_s_sleep(1);
      }
      __syncthreads();
    }

    // A fragments: 64 coherent 8B loads, coalesced, issued as one block
    const unsigned long long* hxr =
        (const unsigned long long*)(hx + (t & 1) * (B_SZ * K2));
    unsigned long long a64[64];
    #pragma unroll
    for (int kk = 0; kk < 32; ++kk) {
      const size_t base = (size_t)(kk * 4 + kg) * 64 + ab2;
      a64[2 * kk]     = __hip_atomic_load(&hxr[base],
                          __ATOMIC_RELAXED, __HIP_MEMORY_SCOPE_AGENT);
      a64[2 * kk + 1] = __hip_atomic_load(&hxr[base + 1],
                          __ATOMIC_RELAXED, __HIP_MEMORY_SCOPE_AGENT);
    }

    f32x4 acc = {0.f, 0.f, 0.f, 0.f};
    #pragma unroll
    for (int kk = 0; kk < 32; ++kk) {
      const uint4 av = make_uint4((uint32_t)a64[2 * kk],
                                  (uint32_t)(a64[2 * kk] >> 32),
                                  (uint32_t)a64[2 * kk + 1],
                                  (uint32_t)(a64[2 * kk + 1] >> 32));
      const uint4 bv = *(const uint4*)(brow + kk * 16 + kg * 4);
      acc = __builtin_amdgcn_mfma_f32_16x16x32_f16(
          __builtin_bit_cast(f16x8, av), __builtin_bit_cast(f16x8, bv),
          acc, 0, 0, 0);
    }

    // liquid update for the 4 owned (b, j) cells
    float hn[4];
    #pragma unroll
    for (int r = 0; r < 4; ++r) {
      const float z = acc[r] + prevC[r];
      const float f = 1.f / (1.f + __expf(-z));
      hn[r] = (h_old[r] + tsC[r] * f * a_j) / (1.f + tsC[r] * (it_j + f));
      h_old[r] = hn[r];
    }

    // publish fragment-major: even-j lanes store pk16(hn_j, hn_{j+1})
    uint32_t* hxw = hx + ((t + 1) & 1) * (B_SZ * K2);
    #pragma unroll
    for (int r = 0; r < 4; ++r) {
      const float partner = __shfl_xor(hn[r], 1);
      if ((row16 & 1) == 0)
        __hip_atomic_store(&hxw[pub_base + (b0 + r) * 4],
                           pk16(hn[r], partner),
                           __ATOMIC_RELAXED, __HIP_MEMORY_SCOPE_AGENT);
    }
    if (bk < 16) {   // motor half -> hseq f32
      #pragma unroll
      for (int r = 0; r < 4; ++r)
        hseq[(size_t)t * (B_SZ * MOT) + (b0 + r) * MOT + j_glob] = hn[r];
    }

    // prefetch next step's pre/ts (overlaps store drain)
    const int tn = (t + 1 < T_SZ) ? t + 1 : t;
    #pragma unroll
    for (int r = 0; r < 4; ++r) {
      prevC[r] = pre[(size_t)tn * (B_SZ * HID) + (b0 + r) * HID + j_glob];
      tsC[r]   = tsp[(b0 + r) * T_SZ + tn];
    }

    __syncthreads();   // every wave drains vmcnt(0) -> hx stores visible

    if (tid == 0)
      __hip_atomic_store(&flags[bk * 16], (uint32_t)(t + 1),
                         __ATOMIC_RELAXED, __HIP_MEMORY_SCOPE_AGENT);
  }

  #pragma unroll
  for (int r = 0; r < 4; ++r)
    last_state[(b0 + r) * HID + j_glob] = h_old[r];
}

extern "C" void kernel_launch(void* const* d_in, const int* in_sizes, int n_in,
                              void* d_out, int out_size, void* d_ws, size_t ws_size,
                              hipStream_t stream)
{
  const float* inputs    = (const float*)d_in[0];
  const float* timespans = (const float*)d_in[1];
  const float* init_h    = (const float*)d_in[2];
  const float* W_in      = (const float*)d_in[3];
  const float* b_in      = (const float*)d_in[4];
  const float* W_x       = (const float*)d_in[5];
  const float* W_h       = (const float*)d_in[6];
  const float* b_cell    = (const float*)d_in[7];
  const float* tau       = (const float*)d_in[8];
  const float* A         = (const float*)d_in[9];
  const float* W_out     = (const float*)d_in[10];
  const float* b_out     = (const float*)d_in[11];
  float* out = (float*)d_out;

  float*    ws    = (float*)d_ws;
  float*    pre   = ws;                                  // T*B*HID f32
  float*    hseq  = pre   + (size_t)T_SZ * B_SZ * HID;   // T*B*MOT f32
  float*    WxiWp = hseq  + (size_t)T_SZ * B_SZ * MOT;   // HID*IN_SZ (Wxi f32 -> Wp16 u32)
  float*    beff  = WxiWp + (size_t)HID * IN_SZ;         // HID
  uint32_t* hx    = (uint32_t*)(beff + HID);             // 2*B*K2
  uint32_t* flags = hx + 2 * B_SZ * K2;                  // NBLK*16 u32

  // K0: Wxi = W_x @ W_in  (fold input projection into cell GEMM)
  gemm_tiled<false><<<dim3(IN_SZ / 64, HID / 64), 256, 0, stream>>>(
      W_x, W_in, nullptr, WxiWp, HID, IN_SZ, SEN, SEN,
      1 << 30, (long long)IN_SZ, 0LL);

  bias_eff_kernel<<<HID / 256, 256, 0, stream>>>(W_x, b_in, b_cell, beff);

  // K1: pre[t][b][h] = inputs[r=b*T+t,:] @ Wxi^T + beff
  gemm_tiled<true><<<dim3(HID / 64, (B_SZ * T_SZ) / 64), 256, 0, stream>>>(
      inputs, WxiWp, beff, pre, B_SZ * T_SZ, HID, IN_SZ, IN_SZ,
      T_SZ, (long long)B_SZ * HID, (long long)HID);

  // K2a: pack W_h -> f16x2 (overwrites Wxi slot; safe by stream order)
  pack_wh16_kernel<<<(HID * K2) / 256, 256, 0, stream>>>(W_h, (uint32_t*)WxiWp);

  // K2b: init exchange buffer parity-0 (fragment-major); zero flags
  init_hx_kernel<<<(B_SZ * K2) / 256, 256, 0, stream>>>(init_h, hx);
  (void)hipMemsetAsync(flags, 0, NBLK * 16 * sizeof(uint32_t), stream);

  // K2c: the scan — 32 co-resident blocks
  {
    const uint32_t* Wp16c = (const uint32_t*)WxiWp;
    float* last_state = out + (size_t)B_SZ * T_SZ * OUT_SZ;
    void* args[] = {
      (void*)&init_h, (void*)&Wp16c, (void*)&pre, (void*)&timespans,
      (void*)&A, (void*)&tau, (void*)&hseq, (void*)&hx, (void*)&flags,
      (void*)&last_state
    };
    (void)hipLaunchCooperativeKernel((void*)scan_x_kernel, dim3(NBLK), dim3(256),
                                     args, 0, stream);
  }

  // K3: out[b][t][o] = hseq[r=t*B+b, :MOT] @ W_out^T + b_out
  gemm_tiled<true><<<dim3(OUT_SZ / 64, (B_SZ * T_SZ) / 64), 256, 0, stream>>>(
      hseq, W_out, b_out, out, B_SZ * T_SZ, OUT_SZ, MOT, MOT,
      B_SZ, (long long)T_SZ * OUT_SZ, (long long)OUT_SZ);
}

// Round 13
// 4288.140 us; speedup vs baseline: 2.3493x; 1.2127x over previous
//
#include <hip/hip_runtime.h>
#include <math.h>

#define B_SZ   32
#define T_SZ   1024
#define IN_SZ  512
#define SEN    512
#define HID    1024
#define MOT    512
#define OUT_SZ 512

#define NBLK   32          // scan blocks (j-slices)
#define JSL    32          // j's per block
#define K2     512         // f16-pair dwords per h row
#define WPAD   516         // padded w_lds row stride (dwords)

typedef __fp16  f16x8 __attribute__((ext_vector_type(8)));
typedef float   f32x4 __attribute__((ext_vector_type(4)));

__device__ inline uint32_t pk16(float a, float b) {
  auto p = __builtin_amdgcn_cvt_pkrtz(a, b);
  return __builtin_bit_cast(uint32_t, p);
}

// ---------------------------------------------------------------------------
// f32 tile GEMM (kept for K0 only): C = A @ B (+bias), generalized scatter
// ---------------------------------------------------------------------------
template<bool TB>
__global__ __launch_bounds__(256) void gemm_tiled(
    const float* __restrict__ A, const float* __restrict__ Bm,
    const float* __restrict__ bias, float* __restrict__ C,
    int M, int N, int K, int lda,
    int P, long long S1, long long S2)
{
  __shared__ float As[16][64 + 1];
  __shared__ float Bs[16][64 + 1];
  const int tid = threadIdx.x;
  const int n0 = blockIdx.x * 64;
  const int r0 = blockIdx.y * 64;
  const int ty = tid / 16;
  const int tx = tid % 16;

  float acc[4][4] = {};

  for (int k0 = 0; k0 < K; k0 += 16) {
    {
      const int kk = tid % 16, m0 = tid / 16;
      #pragma unroll
      for (int i = 0; i < 4; i++) {
        const int m = m0 + i * 16;
        As[kk][m] = A[(long long)(r0 + m) * lda + k0 + kk];
      }
    }
    if (TB) {
      const int kk = tid % 16, nl0 = tid / 16;
      #pragma unroll
      for (int i = 0; i < 4; i++) {
        const int n = nl0 + i * 16;
        Bs[kk][n] = Bm[(long long)(n0 + n) * K + k0 + kk];
      }
    } else {
      const int nl = tid % 64, kk0 = tid / 64;
      #pragma unroll
      for (int i = 0; i < 4; i++) {
        const int kk = kk0 + i * 4;
        Bs[kk][nl] = Bm[(long long)(k0 + kk) * N + n0 + nl];
      }
    }
    __syncthreads();

    #pragma unroll
    for (int kk = 0; kk < 16; kk++) {
      float av[4], bv[4];
      #pragma unroll
      for (int i = 0; i < 4; i++) av[i] = As[kk][ty * 4 + i];
      #pragma unroll
      for (int j = 0; j < 4; j++) bv[j] = Bs[kk][tx * 4 + j];
      #pragma unroll
      for (int i = 0; i < 4; i++)
        #pragma unroll
        for (int j = 0; j < 4; j++)
          acc[i][j] += av[i] * bv[j];
    }
    __syncthreads();
  }

  #pragma unroll
  for (int i = 0; i < 4; i++) {
    const int r = r0 + ty * 4 + i;
    const long long base = (long long)(r % P) * S1 + (long long)(r / P) * S2;
    #pragma unroll
    for (int j = 0; j < 4; j++) {
      const int c = n0 + tx * 4 + j;
      float v = acc[i][j];
      if (bias) v += bias[c];
      C[base + c] = v;
    }
  }
}

// ---------------------------------------------------------------------------
// MFMA f16 GEMM: C[scatter(r), c] = sum_k A[r,k]*B[c,k] + bias[c]
// A16/B16: [M][K/2] / [N][K/2] u32 f16-pairs. 128x128 tile, 4 waves,
// wave = 64x64 (4x4 frags of 16x16x32), BK=32 (16 u32), LDS stride 20
// (16B aligned, 2-way bank alias = free). Frag layout = R8-verified:
// A row16 = M-row, B row16 = N-col, C col=lane&15 row=(lane>>4)*4+reg.
// ---------------------------------------------------------------------------
__global__ __launch_bounds__(256) void gemm_mfma(
    const uint32_t* __restrict__ A16, const uint32_t* __restrict__ B16,
    const float* __restrict__ bias, float* __restrict__ C,
    int K2w, int P, long long S1, long long S2)
{
  __shared__ uint32_t Al[128 * 20];
  __shared__ uint32_t Bl[128 * 20];
  const int tid  = threadIdx.x;
  const int r0   = blockIdx.y * 128;
  const int c0   = blockIdx.x * 128;
  const int wv   = tid >> 6, lane = tid & 63;
  const int wrow = wv >> 1, wcol = wv & 1;
  const int row16 = lane & 15, kg = lane >> 4;

  const int srow = tid >> 1;            // 0..127
  const int scol = (tid & 1) * 8;       // 0 or 8 (u32)

  f32x4 acc[4][4];
  #pragma unroll
  for (int a = 0; a < 4; ++a)
    #pragma unroll
    for (int b = 0; b < 4; ++b) acc[a][b] = (f32x4){0.f, 0.f, 0.f, 0.f};

  const int nkt = K2w / 16;
  for (int kt = 0; kt < nkt; ++kt) {
    const uint32_t* ag = A16 + (size_t)(r0 + srow) * K2w + kt * 16 + scol;
    const uint32_t* bg = B16 + (size_t)(c0 + srow) * K2w + kt * 16 + scol;
    *(uint4*)&Al[srow * 20 + scol]     = *(const uint4*)ag;
    *(uint4*)&Al[srow * 20 + scol + 4] = *(const uint4*)(ag + 4);
    *(uint4*)&Bl[srow * 20 + scol]     = *(const uint4*)bg;
    *(uint4*)&Bl[srow * 20 + scol + 4] = *(const uint4*)(bg + 4);
    __syncthreads();

    uint4 af[4], bf[4];
    #pragma unroll
    for (int f = 0; f < 4; ++f) {
      af[f] = *(const uint4*)&Al[(wrow * 64 + f * 16 + row16) * 20 + kg * 4];
      bf[f] = *(const uint4*)&Bl[(wcol * 64 + f * 16 + row16) * 20 + kg * 4];
    }
    #pragma unroll
    for (int fr = 0; fr < 4; ++fr)
      #pragma unroll
      for (int fc = 0; fc < 4; ++fc)
        acc[fr][fc] = __builtin_amdgcn_mfma_f32_16x16x32_f16(
            __builtin_bit_cast(f16x8, af[fr]), __builtin_bit_cast(f16x8, bf[fc]),
            acc[fr][fc], 0, 0, 0);
    __syncthreads();
  }

  #pragma unroll
  for (int fr = 0; fr < 4; ++fr) {
    #pragma unroll
    for (int reg = 0; reg < 4; ++reg) {
      const int rg = r0 + wrow * 64 + fr * 16 + kg * 4 + reg;
      const long long base = (long long)(rg % P) * S1 + (long long)(rg / P) * S2;
      #pragma unroll
      for (int fc = 0; fc < 4; ++fc) {
        const int cg = c0 + wcol * 64 + fc * 16 + row16;
        C[base + cg] = acc[fr][fc][reg] + (bias ? bias[cg] : 0.f);
      }
    }
  }
}

// bias_eff[h] = b_cell[h] + dot(W_x[h,:], b_in)
__global__ void bias_eff_kernel(const float* __restrict__ Wx,
                                const float* __restrict__ b_in,
                                const float* __restrict__ b_cell,
                                float* __restrict__ bias_eff)
{
  const int h = blockIdx.x * 256 + threadIdx.x;
  float s = b_cell[h];
  for (int k = 0; k < SEN; k++) s += Wx[h * SEN + k] * b_in[k];
  bias_eff[h] = s;
}

// Generic f32 -> f16-pair pack: out[i] = pk16(in[2i], in[2i+1])
__global__ __launch_bounds__(256) void pack16_kernel(
    const float* __restrict__ in, uint32_t* __restrict__ outp)
{
  const size_t idx = (size_t)blockIdx.x * 256 + threadIdx.x;
  const float2 v = *(const float2*)(in + idx * 2);
  outp[idx] = pk16(v.x, v.y);
}

// Pack init_h f32 [B][HID] -> hx[0] in FRAGMENT-MAJOR layout:
//   u32 index = (j2>>2)*128 + b*4 + (j2&3)
__global__ __launch_bounds__(256) void init_hx_kernel(
    const float* __restrict__ init_h, uint32_t* __restrict__ hx0)
{
  const int idx = blockIdx.x * 256 + threadIdx.x;      // b*512 + j2
  const int b  = idx >> 9;
  const int j2 = idx & 511;
  const float2 v = *(const float2*)(init_h + (size_t)b * HID + 2 * j2);
  hx0[(j2 >> 2) * 128 + b * 4 + (j2 & 3)] = pk16(v.x, v.y);
}

// ---------------------------------------------------------------------------
// Scan (R11-proven protocol, unchanged except hseq emitted as f16 pairs):
// 32 blocks x 256 threads, W slice in LDS, fragment-major hx exchange,
// flag-line barrier. hseq16[t][b][j2] = pk16(h_j, h_j+1) for j<512.
// ---------------------------------------------------------------------------
__global__ __launch_bounds__(256, 1) void scan_x_kernel(
    const float* __restrict__ init_h,
    const uint32_t* __restrict__ Wp16,   // [HID][K2]
    const float* __restrict__ pre,       // [T][B][HID]
    const float* __restrict__ tsp,       // [B][T]
    const float* __restrict__ Avec,
    const float* __restrict__ tau,
    uint32_t* __restrict__ hseq16,       // [T][B][256] f16 pairs
    uint32_t* __restrict__ hx,           // [2][B_SZ*K2] fragment-major
    uint32_t* __restrict__ flags,        // [NBLK][16]
    float* __restrict__ last_state)      // [B][HID]
{
  __shared__ uint32_t w_lds[JSL * WPAD];   // 66 KB

  const int bk   = blockIdx.x;
  const int tid  = threadIdx.x;
  const int wv   = tid >> 6;
  const int lane = tid & 63;
  const int qr   = wv >> 1;
  const int qc   = wv & 1;
  const int row16 = lane & 15;
  const int kg    = lane >> 4;

  const int j_loc  = qc * 16 + row16;
  const int j_glob = bk * JSL + j_loc;
  const int b0     = qr * 16 + kg * 4;

  {
    const uint32_t* src = Wp16 + (size_t)bk * JSL * K2;
    for (int i = tid; i < JSL * K2; i += 256)
      w_lds[(i >> 9) * WPAD + (i & (K2 - 1))] = src[i];
  }

  const float a_j  = Avec[j_glob];
  const float it_j = 1.f / tau[j_glob];
  float h_old[4];
  #pragma unroll
  for (int r = 0; r < 4; ++r) h_old[r] = init_h[(b0 + r) * HID + j_glob];

  float prevC[4], tsC[4];
  #pragma unroll
  for (int r = 0; r < 4; ++r) {
    prevC[r] = pre[(size_t)(b0 + r) * HID + j_glob];
    tsC[r]   = tsp[(b0 + r) * T_SZ + 0];
  }

  __syncthreads();

  const uint32_t* brow = &w_lds[j_loc * WPAD];
  const int ab2 = (qr * 16 + row16) * 2;            // u64 base within chunk
  const int pub_base = (j_glob >> 3) * 128 + ((j_glob >> 1) & 3);

  for (int t = 0; t < T_SZ; ++t) {
    if (t > 0) {
      if (tid < 64) {
        const uint32_t tgt = (uint32_t)t;
        while (__hip_atomic_load(&flags[(tid & 31) * 16],
                                 __ATOMIC_RELAXED, __HIP_MEMORY_SCOPE_AGENT) < tgt)
          __builtin_amdgcn_s_sleep(1);
      }
      __syncthreads();
    }

    const unsigned long long* hxr =
        (const unsigned long long*)(hx + (t & 1) * (B_SZ * K2));
    unsigned long long a64[64];
    #pragma unroll
    for (int kk = 0; kk < 32; ++kk) {
      const size_t base = (size_t)(kk * 4 + kg) * 64 + ab2;
      a64[2 * kk]     = __hip_atomic_load(&hxr[base],
                          __ATOMIC_RELAXED, __HIP_MEMORY_SCOPE_AGENT);
      a64[2 * kk + 1] = __hip_atomic_load(&hxr[base + 1],
                          __ATOMIC_RELAXED, __HIP_MEMORY_SCOPE_AGENT);
    }

    f32x4 acc = {0.f, 0.f, 0.f, 0.f};
    #pragma unroll
    for (int kk = 0; kk < 32; ++kk) {
      const uint4 av = make_uint4((uint32_t)a64[2 * kk],
                                  (uint32_t)(a64[2 * kk] >> 32),
                                  (uint32_t)a64[2 * kk + 1],
                                  (uint32_t)(a64[2 * kk + 1] >> 32));
      const uint4 bv = *(const uint4*)(brow + kk * 16 + kg * 4);
      acc = __builtin_amdgcn_mfma_f32_16x16x32_f16(
          __builtin_bit_cast(f16x8, av), __builtin_bit_cast(f16x8, bv),
          acc, 0, 0, 0);
    }

    float hn[4];
    #pragma unroll
    for (int r = 0; r < 4; ++r) {
      const float z = acc[r] + prevC[r];
      const float f = 1.f / (1.f + __expf(-z));
      hn[r] = (h_old[r] + tsC[r] * f * a_j) / (1.f + tsC[r] * (it_j + f));
      h_old[r] = hn[r];
    }

    // pack pairs once; reuse for hx publish AND hseq16
    uint32_t pkv[4];
    #pragma unroll
    for (int r = 0; r < 4; ++r) {
      const float partner = __shfl_xor(hn[r], 1);
      pkv[r] = pk16(hn[r], partner);
    }

    uint32_t* hxw = hx + ((t + 1) & 1) * (B_SZ * K2);
    if ((row16 & 1) == 0) {
      #pragma unroll
      for (int r = 0; r < 4; ++r)
        __hip_atomic_store(&hxw[pub_base + (b0 + r) * 4], pkv[r],
                           __ATOMIC_RELAXED, __HIP_MEMORY_SCOPE_AGENT);
      if (bk < 16) {   // motor half -> hseq16
        #pragma unroll
        for (int r = 0; r < 4; ++r)
          hseq16[(size_t)t * (B_SZ * 256) + (b0 + r) * 256 + (j_glob >> 1)] = pkv[r];
      }
    }

    const int tn = (t + 1 < T_SZ) ? t + 1 : t;
    #pragma unroll
    for (int r = 0; r < 4; ++r) {
      prevC[r] = pre[(size_t)tn * (B_SZ * HID) + (b0 + r) * HID + j_glob];
      tsC[r]   = tsp[(b0 + r) * T_SZ + tn];
    }

    __syncthreads();   // drains vmcnt(0): hx stores globally visible

    if (tid == 0)
      __hip_atomic_store(&flags[bk * 16], (uint32_t)(t + 1),
                         __ATOMIC_RELAXED, __HIP_MEMORY_SCOPE_AGENT);
  }

  #pragma unroll
  for (int r = 0; r < 4; ++r)
    last_state[(b0 + r) * HID + j_glob] = h_old[r];
}

extern "C" void kernel_launch(void* const* d_in, const int* in_sizes, int n_in,
                              void* d_out, int out_size, void* d_ws, size_t ws_size,
                              hipStream_t stream)
{
  const float* inputs    = (const float*)d_in[0];
  const float* timespans = (const float*)d_in[1];
  const float* init_h    = (const float*)d_in[2];
  const float* W_in      = (const float*)d_in[3];
  const float* b_in      = (const float*)d_in[4];
  const float* W_x       = (const float*)d_in[5];
  const float* W_h       = (const float*)d_in[6];
  const float* b_cell    = (const float*)d_in[7];
  const float* tau       = (const float*)d_in[8];
  const float* A         = (const float*)d_in[9];
  const float* W_out     = (const float*)d_in[10];
  const float* b_out     = (const float*)d_in[11];
  float* out = (float*)d_out;

  float*    ws     = (float*)d_ws;
  float*    pre    = ws;                                   // 33,554,432 f (128MB)
  uint32_t* hseq16 = (uint32_t*)(pre + (size_t)T_SZ * B_SZ * HID);  // 8,388,608 u32 (32MB)
  uint32_t* in16   = hseq16 + (size_t)T_SZ * B_SZ * 256;   // 8,388,608 u32 (32MB)
  float*    Wxi    = (float*)(in16 + (size_t)B_SZ * T_SZ * 256);    // 524,288 f (2MB)
  uint32_t* wxi16  = (uint32_t*)(Wxi + (size_t)HID * IN_SZ);        // 262,144 u32 (1MB)
  uint32_t* wh16   = wxi16 + (size_t)HID * (IN_SZ / 2);    // 524,288 u32 (2MB)
  uint32_t* wout16 = wh16 + (size_t)HID * K2;              // 131,072 u32 (0.5MB)
  float*    beff   = (float*)(wout16 + (size_t)OUT_SZ * (MOT / 2)); // 1024 f
  uint32_t* hx     = (uint32_t*)(beff + HID);              // 2*B*K2 u32 (128KB)
  uint32_t* flags  = hx + 2 * B_SZ * K2;                   // 512 u32

  // K0: Wxi = W_x @ W_in (f32)
  gemm_tiled<false><<<dim3(IN_SZ / 64, HID / 64), 256, 0, stream>>>(
      W_x, W_in, nullptr, Wxi, HID, IN_SZ, SEN, SEN,
      1 << 30, (long long)IN_SZ, 0LL);

  bias_eff_kernel<<<HID / 256, 256, 0, stream>>>(W_x, b_in, b_cell, beff);

  // packs: inputs, Wxi (after K0), W_h, W_out
  pack16_kernel<<<(B_SZ * T_SZ * IN_SZ / 2) / 256, 256, 0, stream>>>(inputs, in16);
  pack16_kernel<<<(HID * IN_SZ / 2) / 256, 256, 0, stream>>>(Wxi, wxi16);
  pack16_kernel<<<(HID * HID / 2) / 256, 256, 0, stream>>>(W_h, wh16);
  pack16_kernel<<<(OUT_SZ * MOT / 2) / 256, 256, 0, stream>>>(W_out, wout16);

  // K1 (MFMA): pre[t][b][h] = in16[r=b*T+t,:] @ wxi16^T + beff
  //   scatter: addr = (r%1024)*32768 + (r/1024)*1024 + c
  gemm_mfma<<<dim3(HID / 128, (B_SZ * T_SZ) / 128), 256, 0, stream>>>(
      in16, wxi16, beff, pre, IN_SZ / 2,
      T_SZ, (long long)B_SZ * HID, (long long)HID);

  // init exchange buffer parity-0 (fragment-major); zero flags
  init_hx_kernel<<<(B_SZ * K2) / 256, 256, 0, stream>>>(init_h, hx);
  (void)hipMemsetAsync(flags, 0, NBLK * 16 * sizeof(uint32_t), stream);

  // scan — 32 co-resident blocks (R11 protocol)
  {
    const uint32_t* wh16c = (const uint32_t*)wh16;
    float* last_state = out + (size_t)B_SZ * T_SZ * OUT_SZ;
    void* args[] = {
      (void*)&init_h, (void*)&wh16c, (void*)&pre, (void*)&timespans,
      (void*)&A, (void*)&tau, (void*)&hseq16, (void*)&hx, (void*)&flags,
      (void*)&last_state
    };
    (void)hipLaunchCooperativeKernel((void*)scan_x_kernel, dim3(NBLK), dim3(256),
                                     args, 0, stream);
  }

  // K3 (MFMA): out[b][t][o] = hseq16[r=t*B+b,:] @ wout16^T + b_out
  //   scatter: addr = (r%32)*(T*OUT) + (r/32)*OUT + c
  gemm_mfma<<<dim3(OUT_SZ / 128, (B_SZ * T_SZ) / 128), 256, 0, stream>>>(
      hseq16, wout16, b_out, out, MOT / 2,
      B_SZ, (long long)T_SZ * OUT_SZ, (long long)OUT_SZ);
}